// Round 1
// baseline (2549.037 us; speedup 1.0000x reference)
//
#include <hip/hip_runtime.h>

#define NNODES 100000
#define NEDGES 1600000
#define FIN 256
#define HID 128
#define NG 128

static constexpr float BN_EPS_C = 1e-5f;

__global__ __launch_bounds__(256) void k_deg_init(float* __restrict__ deg) {
    int i = blockIdx.x * 256 + threadIdx.x;
    if (i < NNODES) deg[i] = 1.0f;
}

__global__ __launch_bounds__(256) void k_deg_acc(const int* __restrict__ dst, float* __restrict__ deg) {
    int e = blockIdx.x * 256 + threadIdx.x;
    if (e < NEDGES) atomicAdd(&deg[dst[e]], 1.0f);
}

// in-place: deg -> dis = rsqrt(deg); selfn = 1/deg
__global__ __launch_bounds__(256) void k_norm(float* __restrict__ degdis, float* __restrict__ selfn) {
    int i = blockIdx.x * 256 + threadIdx.x;
    if (i < NNODES) {
        float d = degdis[i];
        degdis[i] = rsqrtf(d);
        selfn[i] = 1.0f / d;
    }
}

// GEMM: out hw[N,128] = A[N,K] @ W[K,128]; also ag = hw*selfn[row] + bias[col]
// tile 64 rows x 128 cols, 256 threads, Kstep 32.
template<int K, bool RELU_IN>
__global__ __launch_bounds__(256) void k_gemm(const float* __restrict__ A,
                                              const float* __restrict__ W,
                                              const float* __restrict__ bias,
                                              const float* __restrict__ selfn,
                                              float* __restrict__ hw,
                                              float* __restrict__ ag) {
    __shared__ float As[32][68];   // [k][row], pad 68 (272B, 16B aligned)
    __shared__ float Bs[32][132];  // [k][col], pad 132 (528B, 16B aligned)
    const int tid = threadIdx.x;
    const int tx = tid & 31;       // col group: cols tx*4 .. +3
    const int ty = tid >> 5;       // row group: rows ty*8 .. +7
    const int m0 = blockIdx.x * 64;
    const int ar = tid >> 2;       // A staging: row 0..63
    const int ak = (tid & 3) * 8;  // A staging: k offset
    const int bk = tid >> 3;       // B staging: k row 0..31
    const int bc = (tid & 7) * 16; // B staging: col offset

    float acc[8][4] = {};

    for (int kt = 0; kt < K; kt += 32) {
        // --- stage A (transposed into LDS) ---
        float4 v0 = {0.f,0.f,0.f,0.f}, v1 = {0.f,0.f,0.f,0.f};
        int grow = m0 + ar;
        if (grow < NNODES) {
            const float* s = A + (size_t)grow * K + kt + ak;
            v0 = *(const float4*)(s);
            v1 = *(const float4*)(s + 4);
            if (RELU_IN) {
                v0.x = fmaxf(v0.x, 0.f); v0.y = fmaxf(v0.y, 0.f);
                v0.z = fmaxf(v0.z, 0.f); v0.w = fmaxf(v0.w, 0.f);
                v1.x = fmaxf(v1.x, 0.f); v1.y = fmaxf(v1.y, 0.f);
                v1.z = fmaxf(v1.z, 0.f); v1.w = fmaxf(v1.w, 0.f);
            }
        }
        As[ak + 0][ar] = v0.x; As[ak + 1][ar] = v0.y;
        As[ak + 2][ar] = v0.z; As[ak + 3][ar] = v0.w;
        As[ak + 4][ar] = v1.x; As[ak + 5][ar] = v1.y;
        As[ak + 6][ar] = v1.z; As[ak + 7][ar] = v1.w;
        // --- stage B ---
        {
            const float* s = W + (size_t)(kt + bk) * HID + bc;
            float4 w0 = *(const float4*)(s);
            float4 w1 = *(const float4*)(s + 4);
            float4 w2 = *(const float4*)(s + 8);
            float4 w3 = *(const float4*)(s + 12);
            *(float4*)&Bs[bk][bc + 0]  = w0;
            *(float4*)&Bs[bk][bc + 4]  = w1;
            *(float4*)&Bs[bk][bc + 8]  = w2;
            *(float4*)&Bs[bk][bc + 12] = w3;
        }
        __syncthreads();
        #pragma unroll
        for (int k = 0; k < 32; ++k) {
            float a[8], b[4];
            *(float4*)(a)     = *(const float4*)&As[k][ty * 8];
            *(float4*)(a + 4) = *(const float4*)&As[k][ty * 8 + 4];
            *(float4*)(b)     = *(const float4*)&Bs[k][tx * 4];
            #pragma unroll
            for (int i = 0; i < 8; ++i)
                #pragma unroll
                for (int j = 0; j < 4; ++j)
                    acc[i][j] = fmaf(a[i], b[j], acc[i][j]);
        }
        __syncthreads();
    }

    // epilogue: hw = acc; ag = acc*selfn + bias
    float4 bb = *(const float4*)&bias[tx * 4];
    #pragma unroll
    for (int i = 0; i < 8; ++i) {
        int r = m0 + ty * 8 + i;
        if (r < NNODES) {
            float sn = selfn[r];
            float4 h;
            h.x = acc[i][0]; h.y = acc[i][1]; h.z = acc[i][2]; h.w = acc[i][3];
            *(float4*)&hw[(size_t)r * HID + tx * 4] = h;
            float4 g;
            g.x = fmaf(h.x, sn, bb.x);
            g.y = fmaf(h.y, sn, bb.y);
            g.z = fmaf(h.z, sn, bb.z);
            g.w = fmaf(h.w, sn, bb.w);
            *(float4*)&ag[(size_t)r * HID + tx * 4] = g;
        }
    }
}

// one thread per (edge, feature); a 64-lane wave covers one edge (uniform idx)
__global__ __launch_bounds__(256) void k_scatter(const int* __restrict__ src,
                                                 const int* __restrict__ dst,
                                                 const float* __restrict__ dis,
                                                 const float* __restrict__ hw,
                                                 float* __restrict__ ag) {
    size_t gid = (size_t)blockIdx.x * 256 + threadIdx.x;
    int e = (int)(gid >> 7);
    int f = (int)(gid & 127);
    int s = src[e], d = dst[e];
    float w = dis[s] * dis[d];
    atomicAdd(&ag[(size_t)d * HID + f], hw[(size_t)s * HID + f] * w);
}

// per-graph mean pool (batch sorted -> binary search) + BatchNorm, writes xb
__global__ __launch_bounds__(128) void k_pool_bn(const float* __restrict__ h,
                                                 const int* __restrict__ batch,
                                                 const float* __restrict__ gamma,
                                                 const float* __restrict__ beta,
                                                 const float* __restrict__ mean,
                                                 const float* __restrict__ var,
                                                 float* __restrict__ xb) {
    int g = blockIdx.x, f = threadIdx.x;
    int a = 0, b = NNODES;
    while (a < b) { int m = (a + b) >> 1; if (batch[m] < g) a = m + 1; else b = m; }
    int s1 = a;
    b = NNODES;
    while (a < b) { int m = (a + b) >> 1; if (batch[m] < g + 1) a = m + 1; else b = m; }
    int e1 = a;
    float sum = 0.f;
    for (int i = s1; i < e1; ++i) sum += fmaxf(0.f, h[(size_t)i * HID + f]);
    float cnt = (float)((e1 - s1) > 0 ? (e1 - s1) : 1);
    float pooled = sum / cnt;
    float xbv = (pooled - mean[f]) * rsqrtf(var[f] + BN_EPS_C) * gamma[f] + beta[f];
    xb[g * HID + f] = xbv;
}

// out2[g,c] = relu(xb[g,:] @ lin_w[:,c] + lin_b[c]); 256 threads = 128 graphs x 2 classes
__global__ __launch_bounds__(256) void k_head(const float* __restrict__ xb,
                                              const float* __restrict__ lw,
                                              const float* __restrict__ lb,
                                              float* __restrict__ out2) {
    int t = threadIdx.x;
    int g = t >> 1, c = t & 1;
    float s = lb[c];
    #pragma unroll
    for (int f = 0; f < HID; ++f) s = fmaf(xb[g * HID + f], lw[f * 2 + c], s);
    out2[t] = fmaxf(s, 0.f);
}

extern "C" void kernel_launch(void* const* d_in, const int* in_sizes, int n_in,
                              void* d_out, int out_size, void* d_ws, size_t ws_size,
                              hipStream_t stream) {
    const float* x     = (const float*)d_in[0];
    const int*   ei    = (const int*)d_in[1];
    const int*   batch = (const int*)d_in[3];
    const float* W1 = (const float*)d_in[4];
    const float* b1 = (const float*)d_in[5];
    const float* W2 = (const float*)d_in[6];
    const float* b2 = (const float*)d_in[7];
    const float* W3 = (const float*)d_in[8];
    const float* b3 = (const float*)d_in[9];
    const float* gamma = (const float*)d_in[10];
    const float* beta  = (const float*)d_in[11];
    const float* mean  = (const float*)d_in[12];
    const float* var   = (const float*)d_in[13];
    const float* lw = (const float*)d_in[14];
    const float* lb = (const float*)d_in[15];
    float* out = (float*)d_out;

    float* HW    = (float*)d_ws;                       // N*128
    float* AG    = HW + (size_t)NNODES * HID;          // N*128
    float* DIS   = AG + (size_t)NNODES * HID;          // N (deg -> dis in place)
    float* SELFN = DIS + NNODES;                       // N

    const int* srcv = ei;
    const int* dstv = ei + NEDGES;

    k_deg_init<<<(NNODES + 255) / 256, 256, 0, stream>>>(DIS);
    k_deg_acc<<<(NEDGES + 255) / 256, 256, 0, stream>>>(dstv, DIS);
    k_norm<<<(NNODES + 255) / 256, 256, 0, stream>>>(DIS, SELFN);

    dim3 gg((NNODES + 63) / 64);
    const int sgrid = (int)(((size_t)NEDGES * HID) / 256);  // 800000

    // layer 1
    k_gemm<FIN, false><<<gg, 256, 0, stream>>>(x, W1, b1, SELFN, HW, AG);
    k_scatter<<<sgrid, 256, 0, stream>>>(srcv, dstv, DIS, HW, AG);
    // layer 2 (in-place A read is safe: each block reads only the rows it writes)
    k_gemm<HID, true><<<gg, 256, 0, stream>>>(AG, W2, b2, SELFN, HW, AG);
    k_scatter<<<sgrid, 256, 0, stream>>>(srcv, dstv, DIS, HW, AG);
    // layer 3
    k_gemm<HID, true><<<gg, 256, 0, stream>>>(AG, W3, b3, SELFN, HW, AG);
    k_scatter<<<sgrid, 256, 0, stream>>>(srcv, dstv, DIS, HW, AG);

    k_pool_bn<<<NG, 128, 0, stream>>>(AG, batch, gamma, beta, mean, var, out);
    k_head<<<1, 256, 0, stream>>>(out, lw, lb, out + (size_t)NG * HID);
}

// Round 2
// 1054.466 us; speedup vs baseline: 2.4174x; 2.4174x over previous
//
#include <hip/hip_runtime.h>

#define NNODES 100000
#define NEDGES 1600000
#define FIN 256
#define HID 128
#define NG 128
#define SB 391   // ceil(NNODES/256)

static constexpr float BN_EPS_C = 1e-5f;

__global__ __launch_bounds__(256) void k_zero_cnt(int* __restrict__ cnt) {
    int i = blockIdx.x * 256 + threadIdx.x;
    if (i < NNODES) cnt[i] = 0;
}

__global__ __launch_bounds__(256) void k_count(const int* __restrict__ dst, int* __restrict__ cnt) {
    int e = blockIdx.x * 256 + threadIdx.x;
    if (e < NEDGES) atomicAdd(&cnt[dst[e]], 1);
}

// dis = rsqrt(1+cnt); selfn = 1/(1+cnt)
__global__ __launch_bounds__(256) void k_norm(const int* __restrict__ cnt,
                                              float* __restrict__ dis,
                                              float* __restrict__ selfn) {
    int i = blockIdx.x * 256 + threadIdx.x;
    if (i < NNODES) {
        float d = 1.0f + (float)cnt[i];
        dis[i] = rsqrtf(d);
        selfn[i] = 1.0f / d;
    }
}

__global__ __launch_bounds__(256) void k_scan1(const int* __restrict__ cnt, int* __restrict__ bsum) {
    __shared__ int s[256];
    int t = threadIdx.x;
    int i = blockIdx.x * 256 + t;
    s[t] = (i < NNODES) ? cnt[i] : 0;
    __syncthreads();
    for (int off = 128; off > 0; off >>= 1) {
        if (t < off) s[t] += s[t + off];
        __syncthreads();
    }
    if (t == 0) bsum[blockIdx.x] = s[0];
}

__global__ __launch_bounds__(512) void k_scan2(int* __restrict__ bsum) {
    __shared__ int s[512];
    int t = threadIdx.x;
    int v = (t < SB) ? bsum[t] : 0;
    s[t] = v;
    __syncthreads();
    for (int off = 1; off < 512; off <<= 1) {
        int a = (t >= off) ? s[t - off] : 0;
        __syncthreads();
        s[t] += a;
        __syncthreads();
    }
    if (t < SB) bsum[t] = s[t] - v;   // exclusive
}

__global__ __launch_bounds__(256) void k_scan3(const int* __restrict__ cnt,
                                               const int* __restrict__ bsum,
                                               int* __restrict__ rowptr,
                                               int* __restrict__ cursor) {
    __shared__ int s[256];
    int t = threadIdx.x;
    int i = blockIdx.x * 256 + t;
    int v = (i < NNODES) ? cnt[i] : 0;
    s[t] = v;
    __syncthreads();
    for (int off = 1; off < 256; off <<= 1) {
        int a = (t >= off) ? s[t - off] : 0;
        __syncthreads();
        s[t] += a;
        __syncthreads();
    }
    int ex = s[t] - v + bsum[blockIdx.x];
    if (i < NNODES) { rowptr[i] = ex; cursor[i] = ex; }
    if (i == 0) rowptr[NNODES] = NEDGES;
}

__global__ __launch_bounds__(256) void k_build(const int* __restrict__ src,
                                               const int* __restrict__ dst,
                                               int* __restrict__ cursor,
                                               int* __restrict__ csr) {
    int e = blockIdx.x * 256 + threadIdx.x;
    if (e < NEDGES) {
        int d = dst[e];
        int pos = atomicAdd(&cursor[d], 1);
        csr[pos] = src[e];
    }
}

// GEMM: hw[N,128] = A[N,K] @ W[K,128]; ag = hw*selfn[row] + bias[col]
template<int K, bool RELU_IN>
__global__ __launch_bounds__(256) void k_gemm(const float* __restrict__ A,
                                              const float* __restrict__ W,
                                              const float* __restrict__ bias,
                                              const float* __restrict__ selfn,
                                              float* __restrict__ hw,
                                              float* __restrict__ ag) {
    __shared__ float As[32][68];
    __shared__ float Bs[32][132];
    const int tid = threadIdx.x;
    const int tx = tid & 31;
    const int ty = tid >> 5;
    const int m0 = blockIdx.x * 64;
    const int ar = tid >> 2;
    const int ak = (tid & 3) * 8;
    const int bk = tid >> 3;
    const int bc = (tid & 7) * 16;

    float acc[8][4] = {};

    for (int kt = 0; kt < K; kt += 32) {
        float4 v0 = {0.f,0.f,0.f,0.f}, v1 = {0.f,0.f,0.f,0.f};
        int grow = m0 + ar;
        if (grow < NNODES) {
            const float* s = A + (size_t)grow * K + kt + ak;
            v0 = *(const float4*)(s);
            v1 = *(const float4*)(s + 4);
            if (RELU_IN) {
                v0.x = fmaxf(v0.x, 0.f); v0.y = fmaxf(v0.y, 0.f);
                v0.z = fmaxf(v0.z, 0.f); v0.w = fmaxf(v0.w, 0.f);
                v1.x = fmaxf(v1.x, 0.f); v1.y = fmaxf(v1.y, 0.f);
                v1.z = fmaxf(v1.z, 0.f); v1.w = fmaxf(v1.w, 0.f);
            }
        }
        As[ak + 0][ar] = v0.x; As[ak + 1][ar] = v0.y;
        As[ak + 2][ar] = v0.z; As[ak + 3][ar] = v0.w;
        As[ak + 4][ar] = v1.x; As[ak + 5][ar] = v1.y;
        As[ak + 6][ar] = v1.z; As[ak + 7][ar] = v1.w;
        {
            const float* s = W + (size_t)(kt + bk) * HID + bc;
            float4 w0 = *(const float4*)(s);
            float4 w1 = *(const float4*)(s + 4);
            float4 w2 = *(const float4*)(s + 8);
            float4 w3 = *(const float4*)(s + 12);
            *(float4*)&Bs[bk][bc + 0]  = w0;
            *(float4*)&Bs[bk][bc + 4]  = w1;
            *(float4*)&Bs[bk][bc + 8]  = w2;
            *(float4*)&Bs[bk][bc + 12] = w3;
        }
        __syncthreads();
        #pragma unroll
        for (int k = 0; k < 32; ++k) {
            float a[8], b[4];
            *(float4*)(a)     = *(const float4*)&As[k][ty * 8];
            *(float4*)(a + 4) = *(const float4*)&As[k][ty * 8 + 4];
            *(float4*)(b)     = *(const float4*)&Bs[k][tx * 4];
            #pragma unroll
            for (int i = 0; i < 8; ++i)
                #pragma unroll
                for (int j = 0; j < 4; ++j)
                    acc[i][j] = fmaf(a[i], b[j], acc[i][j]);
        }
        __syncthreads();
    }

    float4 bb = *(const float4*)&bias[tx * 4];
    #pragma unroll
    for (int i = 0; i < 8; ++i) {
        int r = m0 + ty * 8 + i;
        if (r < NNODES) {
            float sn = selfn[r];
            float4 h;
            h.x = acc[i][0]; h.y = acc[i][1]; h.z = acc[i][2]; h.w = acc[i][3];
            *(float4*)&hw[(size_t)r * HID + tx * 4] = h;
            float4 g;
            g.x = fmaf(h.x, sn, bb.x);
            g.y = fmaf(h.y, sn, bb.y);
            g.z = fmaf(h.z, sn, bb.z);
            g.w = fmaf(h.w, sn, bb.w);
            *(float4*)&ag[(size_t)r * HID + tx * 4] = g;
        }
    }
}

// one wave per node; lane handles 2 features. ag[node] += sum_e w_e * hw[src_e]
__global__ __launch_bounds__(256) void k_gather(const int* __restrict__ rowptr,
                                                const int* __restrict__ csr,
                                                const float* __restrict__ dis,
                                                const float* __restrict__ hw,
                                                float* __restrict__ ag) {
    int node = blockIdx.x * 4 + (threadIdx.x >> 6);
    if (node >= NNODES) return;
    int lane = threadIdx.x & 63;
    int beg = rowptr[node], end = rowptr[node + 1];
    float dd = dis[node];
    float2* agp = (float2*)&ag[(size_t)node * HID + lane * 2];
    float2 acc = *agp;
    int e = beg;
    for (; e + 1 < end; e += 2) {
        int s0 = csr[e], s1 = csr[e + 1];
        float w0 = dis[s0] * dd, w1 = dis[s1] * dd;
        float2 h0 = *(const float2*)&hw[(size_t)s0 * HID + lane * 2];
        float2 h1 = *(const float2*)&hw[(size_t)s1 * HID + lane * 2];
        acc.x += h0.x * w0 + h1.x * w1;
        acc.y += h0.y * w0 + h1.y * w1;
    }
    if (e < end) {
        int s0 = csr[e];
        float w0 = dis[s0] * dd;
        float2 h0 = *(const float2*)&hw[(size_t)s0 * HID + lane * 2];
        acc.x += h0.x * w0;
        acc.y += h0.y * w0;
    }
    *agp = acc;
}

__global__ __launch_bounds__(128) void k_pool_bn(const float* __restrict__ h,
                                                 const int* __restrict__ batch,
                                                 const float* __restrict__ gamma,
                                                 const float* __restrict__ beta,
                                                 const float* __restrict__ mean,
                                                 const float* __restrict__ var,
                                                 float* __restrict__ xb) {
    int g = blockIdx.x, f = threadIdx.x;
    int a = 0, b = NNODES;
    while (a < b) { int m = (a + b) >> 1; if (batch[m] < g) a = m + 1; else b = m; }
    int s1 = a;
    b = NNODES;
    while (a < b) { int m = (a + b) >> 1; if (batch[m] < g + 1) a = m + 1; else b = m; }
    int e1 = a;
    float sum = 0.f;
    for (int i = s1; i < e1; ++i) sum += fmaxf(0.f, h[(size_t)i * HID + f]);
    float cnt = (float)((e1 - s1) > 0 ? (e1 - s1) : 1);
    float pooled = sum / cnt;
    float xbv = (pooled - mean[f]) * rsqrtf(var[f] + BN_EPS_C) * gamma[f] + beta[f];
    xb[g * HID + f] = xbv;
}

__global__ __launch_bounds__(256) void k_head(const float* __restrict__ xb,
                                              const float* __restrict__ lw,
                                              const float* __restrict__ lb,
                                              float* __restrict__ out2) {
    int t = threadIdx.x;
    int g = t >> 1, c = t & 1;
    float s = lb[c];
    #pragma unroll
    for (int f = 0; f < HID; ++f) s = fmaf(xb[g * HID + f], lw[f * 2 + c], s);
    out2[t] = fmaxf(s, 0.f);
}

extern "C" void kernel_launch(void* const* d_in, const int* in_sizes, int n_in,
                              void* d_out, int out_size, void* d_ws, size_t ws_size,
                              hipStream_t stream) {
    const float* x     = (const float*)d_in[0];
    const int*   ei    = (const int*)d_in[1];
    const int*   batch = (const int*)d_in[3];
    const float* W1 = (const float*)d_in[4];
    const float* b1 = (const float*)d_in[5];
    const float* W2 = (const float*)d_in[6];
    const float* b2 = (const float*)d_in[7];
    const float* W3 = (const float*)d_in[8];
    const float* b3 = (const float*)d_in[9];
    const float* gamma = (const float*)d_in[10];
    const float* beta  = (const float*)d_in[11];
    const float* mean  = (const float*)d_in[12];
    const float* var   = (const float*)d_in[13];
    const float* lw = (const float*)d_in[14];
    const float* lb = (const float*)d_in[15];
    float* out = (float*)d_out;

    // workspace layout (floats/ints are 4B each)
    float* HW     = (float*)d_ws;                      // N*128 f
    float* AG     = HW + (size_t)NNODES * HID;         // N*128 f
    float* DIS    = AG + (size_t)NNODES * HID;         // N f
    float* SELFN  = DIS + NNODES;                      // N f
    int*   CNT    = (int*)(SELFN + NNODES);            // N i
    int*   ROWPTR = CNT + NNODES;                      // N+1 i
    int*   CURSOR = ROWPTR + NNODES + 1;               // N i
    int*   BSUM   = CURSOR + NNODES;                   // SB i
    int*   CSR    = BSUM + ((SB + 63) & ~63);          // E i

    const int* srcv = ei;
    const int* dstv = ei + NEDGES;

    const int gN = (NNODES + 255) / 256;
    const int gE = (NEDGES + 255) / 256;

    // ---- CSR build (once) ----
    k_zero_cnt<<<gN, 256, 0, stream>>>(CNT);
    k_count<<<gE, 256, 0, stream>>>(dstv, CNT);
    k_norm<<<gN, 256, 0, stream>>>(CNT, DIS, SELFN);
    k_scan1<<<SB, 256, 0, stream>>>(CNT, BSUM);
    k_scan2<<<1, 512, 0, stream>>>(BSUM);
    k_scan3<<<SB, 256, 0, stream>>>(CNT, BSUM, ROWPTR, CURSOR);
    k_build<<<gE, 256, 0, stream>>>(srcv, dstv, CURSOR, CSR);

    dim3 gg((NNODES + 63) / 64);
    const int ggat = (NNODES + 3) / 4;

    // layer 1
    k_gemm<FIN, false><<<gg, 256, 0, stream>>>(x, W1, b1, SELFN, HW, AG);
    k_gather<<<ggat, 256, 0, stream>>>(ROWPTR, CSR, DIS, HW, AG);
    // layer 2
    k_gemm<HID, true><<<gg, 256, 0, stream>>>(AG, W2, b2, SELFN, HW, AG);
    k_gather<<<ggat, 256, 0, stream>>>(ROWPTR, CSR, DIS, HW, AG);
    // layer 3
    k_gemm<HID, true><<<gg, 256, 0, stream>>>(AG, W3, b3, SELFN, HW, AG);
    k_gather<<<ggat, 256, 0, stream>>>(ROWPTR, CSR, DIS, HW, AG);

    k_pool_bn<<<NG, 128, 0, stream>>>(AG, batch, gamma, beta, mean, var, out);
    k_head<<<1, 256, 0, stream>>>(out, lw, lb, out + (size_t)NG * HID);
}

// Round 3
// 992.822 us; speedup vs baseline: 2.5675x; 1.0621x over previous
//
#include <hip/hip_runtime.h>

#define NNODES 100000
#define NEDGES 1600000
#define FIN 256
#define HID 128
#define NG 128
#define SB 391            // ceil(NNODES/256)
#define NBUCK 1563        // ceil(NNODES/64)

static constexpr float BN_EPS_C = 1e-5f;

__global__ __launch_bounds__(256) void k_zero_cnt(int* __restrict__ cnt) {
    int i = blockIdx.x * 256 + threadIdx.x;
    if (i < NNODES) cnt[i] = 0;
}

__global__ __launch_bounds__(256) void k_count(const int* __restrict__ dst, int* __restrict__ cnt) {
    int e = blockIdx.x * 256 + threadIdx.x;
    if (e < NEDGES) atomicAdd(&cnt[dst[e]], 1);
}

// dis = rsqrt(1+cnt); selfn = 1/(1+cnt)
__global__ __launch_bounds__(256) void k_norm(const int* __restrict__ cnt,
                                              float* __restrict__ dis,
                                              float* __restrict__ selfn) {
    int i = blockIdx.x * 256 + threadIdx.x;
    if (i < NNODES) {
        float d = 1.0f + (float)cnt[i];
        dis[i] = rsqrtf(d);
        selfn[i] = 1.0f / d;
    }
}

__global__ __launch_bounds__(256) void k_scan1(const int* __restrict__ cnt, int* __restrict__ bsum) {
    __shared__ int s[256];
    int t = threadIdx.x;
    int i = blockIdx.x * 256 + t;
    s[t] = (i < NNODES) ? cnt[i] : 0;
    __syncthreads();
    for (int off = 128; off > 0; off >>= 1) {
        if (t < off) s[t] += s[t + off];
        __syncthreads();
    }
    if (t == 0) bsum[blockIdx.x] = s[0];
}

__global__ __launch_bounds__(512) void k_scan2(int* __restrict__ bsum) {
    __shared__ int s[512];
    int t = threadIdx.x;
    int v = (t < SB) ? bsum[t] : 0;
    s[t] = v;
    __syncthreads();
    for (int off = 1; off < 512; off <<= 1) {
        int a = (t >= off) ? s[t - off] : 0;
        __syncthreads();
        s[t] += a;
        __syncthreads();
    }
    if (t < SB) bsum[t] = s[t] - v;   // exclusive
}

__global__ __launch_bounds__(256) void k_scan3(const int* __restrict__ cnt,
                                               const int* __restrict__ bsum,
                                               int* __restrict__ rowptr) {
    __shared__ int s[256];
    int t = threadIdx.x;
    int i = blockIdx.x * 256 + t;
    int v = (i < NNODES) ? cnt[i] : 0;
    s[t] = v;
    __syncthreads();
    for (int off = 1; off < 256; off <<= 1) {
        int a = (t >= off) ? s[t - off] : 0;
        __syncthreads();
        s[t] += a;
        __syncthreads();
    }
    int ex = s[t] - v + bsum[blockIdx.x];
    if (i < NNODES) rowptr[i] = ex;
    if (i == 0) rowptr[NNODES] = NEDGES;
}

// bucket cursors = rowptr at bucket starts
__global__ __launch_bounds__(256) void kb0(const int* __restrict__ rowptr, int* __restrict__ bcur) {
    int b = blockIdx.x * 256 + threadIdx.x;
    if (b < NBUCK) bcur[b] = rowptr[b * 64];
}

// scatter packed (src<<6 | dstLow) into the bucket's contiguous CSR region
__global__ __launch_bounds__(256) void kb1(const int* __restrict__ src,
                                           const int* __restrict__ dst,
                                           int* __restrict__ bcur,
                                           int* __restrict__ pairs) {
    int e = blockIdx.x * 256 + threadIdx.x;
    if (e < NEDGES) {
        int d = dst[e];
        int pos = atomicAdd(&bcur[d >> 6], 1);
        pairs[pos] = (src[e] << 6) | (d & 63);
    }
}

// within-bucket placement via LDS per-node cursors
__global__ __launch_bounds__(256) void kb2(const int* __restrict__ rowptr,
                                           const int* __restrict__ pairs,
                                           int* __restrict__ csr) {
    int b = blockIdx.x;
    int nbase = b * 64;
    int nmax = NNODES - nbase; if (nmax > 64) nmax = 64;
    __shared__ int cur[64];
    int t = threadIdx.x;
    if (t < nmax) cur[t] = rowptr[nbase + t];
    __syncthreads();
    int beg = rowptr[nbase];
    int end = rowptr[nbase + nmax];
    for (int i = beg + t; i < end; i += 256) {
        int p = pairs[i];
        int pos = atomicAdd(&cur[p & 63], 1);
        csr[pos] = p >> 6;
    }
}

// GEMM: hw[N,128] = A[N,K] @ W[K,128]; ag = hw*selfn[row] + bias[col]
template<int K, bool RELU_IN>
__global__ __launch_bounds__(256) void k_gemm(const float* __restrict__ A,
                                              const float* __restrict__ W,
                                              const float* __restrict__ bias,
                                              const float* __restrict__ selfn,
                                              float* __restrict__ hw,
                                              float* __restrict__ ag) {
    __shared__ float As[32][68];
    __shared__ float Bs[32][132];
    const int tid = threadIdx.x;
    const int tx = tid & 31;
    const int ty = tid >> 5;
    const int m0 = blockIdx.x * 64;
    const int ar = tid >> 2;
    const int ak = (tid & 3) * 8;
    const int bk = tid >> 3;
    const int bc = (tid & 7) * 16;

    float acc[8][4] = {};

    for (int kt = 0; kt < K; kt += 32) {
        float4 v0 = {0.f,0.f,0.f,0.f}, v1 = {0.f,0.f,0.f,0.f};
        int grow = m0 + ar;
        if (grow < NNODES) {
            const float* s = A + (size_t)grow * K + kt + ak;
            v0 = *(const float4*)(s);
            v1 = *(const float4*)(s + 4);
            if (RELU_IN) {
                v0.x = fmaxf(v0.x, 0.f); v0.y = fmaxf(v0.y, 0.f);
                v0.z = fmaxf(v0.z, 0.f); v0.w = fmaxf(v0.w, 0.f);
                v1.x = fmaxf(v1.x, 0.f); v1.y = fmaxf(v1.y, 0.f);
                v1.z = fmaxf(v1.z, 0.f); v1.w = fmaxf(v1.w, 0.f);
            }
        }
        As[ak + 0][ar] = v0.x; As[ak + 1][ar] = v0.y;
        As[ak + 2][ar] = v0.z; As[ak + 3][ar] = v0.w;
        As[ak + 4][ar] = v1.x; As[ak + 5][ar] = v1.y;
        As[ak + 6][ar] = v1.z; As[ak + 7][ar] = v1.w;
        {
            const float* s = W + (size_t)(kt + bk) * HID + bc;
            float4 w0 = *(const float4*)(s);
            float4 w1 = *(const float4*)(s + 4);
            float4 w2 = *(const float4*)(s + 8);
            float4 w3 = *(const float4*)(s + 12);
            *(float4*)&Bs[bk][bc + 0]  = w0;
            *(float4*)&Bs[bk][bc + 4]  = w1;
            *(float4*)&Bs[bk][bc + 8]  = w2;
            *(float4*)&Bs[bk][bc + 12] = w3;
        }
        __syncthreads();
        #pragma unroll
        for (int k = 0; k < 32; ++k) {
            float a[8], b[4];
            *(float4*)(a)     = *(const float4*)&As[k][ty * 8];
            *(float4*)(a + 4) = *(const float4*)&As[k][ty * 8 + 4];
            *(float4*)(b)     = *(const float4*)&Bs[k][tx * 4];
            #pragma unroll
            for (int i = 0; i < 8; ++i)
                #pragma unroll
                for (int j = 0; j < 4; ++j)
                    acc[i][j] = fmaf(a[i], b[j], acc[i][j]);
        }
        __syncthreads();
    }

    float4 bb = *(const float4*)&bias[tx * 4];
    #pragma unroll
    for (int i = 0; i < 8; ++i) {
        int r = m0 + ty * 8 + i;
        if (r < NNODES) {
            float sn = selfn[r];
            float4 h;
            h.x = acc[i][0]; h.y = acc[i][1]; h.z = acc[i][2]; h.w = acc[i][3];
            *(float4*)&hw[(size_t)r * HID + tx * 4] = h;
            float4 g;
            g.x = fmaf(h.x, sn, bb.x);
            g.y = fmaf(h.y, sn, bb.y);
            g.z = fmaf(h.z, sn, bb.z);
            g.w = fmaf(h.w, sn, bb.w);
            *(float4*)&ag[(size_t)r * HID + tx * 4] = g;
        }
    }
}

// one wave per node; lane handles 2 features
__global__ __launch_bounds__(256) void k_gather(const int* __restrict__ rowptr,
                                                const int* __restrict__ csr,
                                                const float* __restrict__ dis,
                                                const float* __restrict__ hw,
                                                float* __restrict__ ag) {
    int node = blockIdx.x * 4 + (threadIdx.x >> 6);
    if (node >= NNODES) return;
    int lane = threadIdx.x & 63;
    int beg = rowptr[node], end = rowptr[node + 1];
    float dd = dis[node];
    float2* agp = (float2*)&ag[(size_t)node * HID + lane * 2];
    float2 acc = *agp;
    int e = beg;
    for (; e + 1 < end; e += 2) {
        int s0 = csr[e], s1 = csr[e + 1];
        float w0 = dis[s0] * dd, w1 = dis[s1] * dd;
        float2 h0 = *(const float2*)&hw[(size_t)s0 * HID + lane * 2];
        float2 h1 = *(const float2*)&hw[(size_t)s1 * HID + lane * 2];
        acc.x += h0.x * w0 + h1.x * w1;
        acc.y += h0.y * w0 + h1.y * w1;
    }
    if (e < end) {
        int s0 = csr[e];
        float w0 = dis[s0] * dd;
        float2 h0 = *(const float2*)&hw[(size_t)s0 * HID + lane * 2];
        acc.x += h0.x * w0;
        acc.y += h0.y * w0;
    }
    *agp = acc;
}

// one graph per block, 1024 threads: 8 rows in flight per feature
__global__ __launch_bounds__(1024) void k_pool_bn(const float* __restrict__ h,
                                                  const int* __restrict__ batch,
                                                  const float* __restrict__ gamma,
                                                  const float* __restrict__ beta,
                                                  const float* __restrict__ mean,
                                                  const float* __restrict__ var,
                                                  float* __restrict__ xb) {
    int g = blockIdx.x;
    int tid = threadIdx.x;
    int f = tid & 127, r = tid >> 7;   // r in 0..7
    int a = 0, b = NNODES;
    while (a < b) { int m = (a + b) >> 1; if (batch[m] < g) a = m + 1; else b = m; }
    int s1 = a;
    b = NNODES;
    while (a < b) { int m = (a + b) >> 1; if (batch[m] < g + 1) a = m + 1; else b = m; }
    int e1 = a;
    float sum = 0.f;
    for (int i = s1 + r; i < e1; i += 8) sum += fmaxf(0.f, h[(size_t)i * HID + f]);
    __shared__ float red[8][128];
    red[r][f] = sum;
    __syncthreads();
    if (r == 0) {
        float s = red[0][f] + red[1][f] + red[2][f] + red[3][f]
                + red[4][f] + red[5][f] + red[6][f] + red[7][f];
        float cnt = (float)((e1 - s1) > 0 ? (e1 - s1) : 1);
        float pooled = s / cnt;
        float xbv = (pooled - mean[f]) * rsqrtf(var[f] + BN_EPS_C) * gamma[f] + beta[f];
        xb[g * HID + f] = xbv;
    }
}

__global__ __launch_bounds__(256) void k_head(const float* __restrict__ xb,
                                              const float* __restrict__ lw,
                                              const float* __restrict__ lb,
                                              float* __restrict__ out2) {
    int t = threadIdx.x;
    int g = t >> 1, c = t & 1;
    float s = lb[c];
    #pragma unroll
    for (int f = 0; f < HID; ++f) s = fmaf(xb[g * HID + f], lw[f * 2 + c], s);
    out2[t] = fmaxf(s, 0.f);
}

extern "C" void kernel_launch(void* const* d_in, const int* in_sizes, int n_in,
                              void* d_out, int out_size, void* d_ws, size_t ws_size,
                              hipStream_t stream) {
    const float* x     = (const float*)d_in[0];
    const int*   ei    = (const int*)d_in[1];
    const int*   batch = (const int*)d_in[3];
    const float* W1 = (const float*)d_in[4];
    const float* b1 = (const float*)d_in[5];
    const float* W2 = (const float*)d_in[6];
    const float* b2 = (const float*)d_in[7];
    const float* W3 = (const float*)d_in[8];
    const float* b3 = (const float*)d_in[9];
    const float* gamma = (const float*)d_in[10];
    const float* beta  = (const float*)d_in[11];
    const float* mean  = (const float*)d_in[12];
    const float* var   = (const float*)d_in[13];
    const float* lw = (const float*)d_in[14];
    const float* lb = (const float*)d_in[15];
    float* out = (float*)d_out;

    float* HW     = (float*)d_ws;                      // N*128 f
    float* AG     = HW + (size_t)NNODES * HID;         // N*128 f
    float* DIS    = AG + (size_t)NNODES * HID;         // N f
    float* SELFN  = DIS + NNODES;                      // N f
    int*   CNT    = (int*)(SELFN + NNODES);            // N i
    int*   ROWPTR = CNT + NNODES;                      // N+1 i
    int*   BSUM   = ROWPTR + NNODES + 64;              // SB i
    int*   CSR    = BSUM + ((SB + 63) & ~63);          // E i
    // build-phase aliases (dead before first gemm writes HW/AG)
    int*   PAIRS  = (int*)HW;                          // E i
    int*   BCUR   = (int*)AG;                          // NBUCK i

    const int* srcv = ei;
    const int* dstv = ei + NEDGES;

    const int gN = (NNODES + 255) / 256;
    const int gE = (NEDGES + 255) / 256;

    // ---- CSR build ----
    k_zero_cnt<<<gN, 256, 0, stream>>>(CNT);
    k_count<<<gE, 256, 0, stream>>>(dstv, CNT);
    k_norm<<<gN, 256, 0, stream>>>(CNT, DIS, SELFN);
    k_scan1<<<SB, 256, 0, stream>>>(CNT, BSUM);
    k_scan2<<<1, 512, 0, stream>>>(BSUM);
    k_scan3<<<SB, 256, 0, stream>>>(CNT, BSUM, ROWPTR);
    kb0<<<(NBUCK + 255) / 256, 256, 0, stream>>>(ROWPTR, BCUR);
    kb1<<<gE, 256, 0, stream>>>(srcv, dstv, BCUR, PAIRS);
    kb2<<<NBUCK, 256, 0, stream>>>(ROWPTR, PAIRS, CSR);

    dim3 gg((NNODES + 63) / 64);
    const int ggat = (NNODES + 3) / 4;

    // layer 1
    k_gemm<FIN, false><<<gg, 256, 0, stream>>>(x, W1, b1, SELFN, HW, AG);
    k_gather<<<ggat, 256, 0, stream>>>(ROWPTR, CSR, DIS, HW, AG);
    // layer 2
    k_gemm<HID, true><<<gg, 256, 0, stream>>>(AG, W2, b2, SELFN, HW, AG);
    k_gather<<<ggat, 256, 0, stream>>>(ROWPTR, CSR, DIS, HW, AG);
    // layer 3
    k_gemm<HID, true><<<gg, 256, 0, stream>>>(AG, W3, b3, SELFN, HW, AG);
    k_gather<<<ggat, 256, 0, stream>>>(ROWPTR, CSR, DIS, HW, AG);

    k_pool_bn<<<NG, 1024, 0, stream>>>(AG, batch, gamma, beta, mean, var, out);
    k_head<<<1, 256, 0, stream>>>(out, lw, lb, out + (size_t)NG * HID);
}

// Round 4
// 783.195 us; speedup vs baseline: 3.2547x; 1.2677x over previous
//
#include <hip/hip_runtime.h>

#define NNODES 100000
#define NEDGES 1600000
#define FIN 256
#define HID 128
#define NG 128
#define SB 391            // ceil(NNODES/256)
#define NB 391            // buckets of 256 nodes (dst>>8)
#define NW 256            // histogram workgroups
#define EPW 6250          // NEDGES / NW

static constexpr float BN_EPS_C = 1e-5f;

__global__ __launch_bounds__(256) void k_zero_cnt(int* __restrict__ cnt) {
    int i = blockIdx.x * 256 + threadIdx.x;
    if (i < NNODES) cnt[i] = 0;
}

__global__ __launch_bounds__(256) void k_count(const int* __restrict__ dst, int* __restrict__ cnt) {
    int e = blockIdx.x * 256 + threadIdx.x;
    if (e < NEDGES) atomicAdd(&cnt[dst[e]], 1);
}

// dis = rsqrt(1+cnt); selfn = 1/(1+cnt)
__global__ __launch_bounds__(256) void k_norm(const int* __restrict__ cnt,
                                              float* __restrict__ dis,
                                              float* __restrict__ selfn) {
    int i = blockIdx.x * 256 + threadIdx.x;
    if (i < NNODES) {
        float d = 1.0f + (float)cnt[i];
        dis[i] = rsqrtf(d);
        selfn[i] = 1.0f / d;
    }
}

__global__ __launch_bounds__(256) void k_scan1(const int* __restrict__ cnt, int* __restrict__ bsum) {
    __shared__ int s[256];
    int t = threadIdx.x;
    int i = blockIdx.x * 256 + t;
    s[t] = (i < NNODES) ? cnt[i] : 0;
    __syncthreads();
    for (int off = 128; off > 0; off >>= 1) {
        if (t < off) s[t] += s[t + off];
        __syncthreads();
    }
    if (t == 0) bsum[blockIdx.x] = s[0];
}

__global__ __launch_bounds__(512) void k_scan2(int* __restrict__ bsum) {
    __shared__ int s[512];
    int t = threadIdx.x;
    int v = (t < SB) ? bsum[t] : 0;
    s[t] = v;
    __syncthreads();
    for (int off = 1; off < 512; off <<= 1) {
        int a = (t >= off) ? s[t - off] : 0;
        __syncthreads();
        s[t] += a;
        __syncthreads();
    }
    if (t < SB) bsum[t] = s[t] - v;   // exclusive
}

__global__ __launch_bounds__(256) void k_scan3(const int* __restrict__ cnt,
                                               const int* __restrict__ bsum,
                                               int* __restrict__ rowptr) {
    __shared__ int s[256];
    int t = threadIdx.x;
    int i = blockIdx.x * 256 + t;
    int v = (i < NNODES) ? cnt[i] : 0;
    s[t] = v;
    __syncthreads();
    for (int off = 1; off < 256; off <<= 1) {
        int a = (t >= off) ? s[t - off] : 0;
        __syncthreads();
        s[t] += a;
        __syncthreads();
    }
    int ex = s[t] - v + bsum[blockIdx.x];
    if (i < NNODES) rowptr[i] = ex;
    if (i == 0) rowptr[NNODES] = NEDGES;
}

// pass A: per-WG LDS histogram over 391 buckets
__global__ __launch_bounds__(256) void kbA(const int* __restrict__ dst, int* __restrict__ hist) {
    __shared__ int h[NB];
    int w = blockIdx.x, t = threadIdx.x;
    for (int i = t; i < NB; i += 256) h[i] = 0;
    __syncthreads();
    int base = w * EPW;
    for (int i = t; i < EPW; i += 256) atomicAdd(&h[dst[base + i] >> 8], 1);
    __syncthreads();
    for (int i = t; i < NB; i += 256) hist[i * NW + w] = h[i];
}

// pass B: per-bucket exclusive scan across WGs + bucket base
__global__ __launch_bounds__(256) void kbB(const int* __restrict__ rowptr,
                                           const int* __restrict__ hist,
                                           int* __restrict__ off) {
    __shared__ int s[NW];
    int b = blockIdx.x, t = threadIdx.x;
    int v = hist[b * NW + t];
    s[t] = v;
    __syncthreads();
    for (int o = 1; o < NW; o <<= 1) {
        int a = (t >= o) ? s[t - o] : 0;
        __syncthreads();
        s[t] += a;
        __syncthreads();
    }
    off[b * NW + t] = s[t] - v + rowptr[b * 256];
}

// pass C: scatter packed (src<<8 | dstLow) to exact disjoint positions
__global__ __launch_bounds__(256) void kbC(const int* __restrict__ src,
                                           const int* __restrict__ dst,
                                           const int* __restrict__ off,
                                           int* __restrict__ pairs) {
    __shared__ int cur[NB];
    int w = blockIdx.x, t = threadIdx.x;
    for (int i = t; i < NB; i += 256) cur[i] = off[i * NW + w];
    __syncthreads();
    int base = w * EPW;
    for (int i = t; i < EPW; i += 256) {
        int d = dst[base + i];
        int pos = atomicAdd(&cur[d >> 8], 1);
        pairs[pos] = (src[base + i] << 8) | (d & 255);
    }
}

// within-bucket placement via LDS per-node cursors (256 nodes/bucket)
__global__ __launch_bounds__(256) void kb2(const int* __restrict__ rowptr,
                                           const int* __restrict__ pairs,
                                           int* __restrict__ csr) {
    int b = blockIdx.x;
    int nbase = b * 256;
    int nmax = NNODES - nbase; if (nmax > 256) nmax = 256;
    __shared__ int cur[256];
    int t = threadIdx.x;
    if (t < nmax) cur[t] = rowptr[nbase + t];
    __syncthreads();
    int beg = rowptr[nbase];
    int end = rowptr[nbase + nmax];
    for (int i = beg + t; i < end; i += 256) {
        int p = pairs[i];
        int pos = atomicAdd(&cur[p & 255], 1);
        csr[pos] = p >> 8;
    }
}

// GEMM: hw[N,128] = A[N,K] @ W[K,128]; ag = hw*selfn[row] + bias[col]
template<int K, bool RELU_IN>
__global__ __launch_bounds__(256) void k_gemm(const float* __restrict__ A,
                                              const float* __restrict__ W,
                                              const float* __restrict__ bias,
                                              const float* __restrict__ selfn,
                                              float* __restrict__ hw,
                                              float* __restrict__ ag) {
    __shared__ float As[32][68];
    __shared__ float Bs[32][132];
    const int tid = threadIdx.x;
    const int tx = tid & 31;
    const int ty = tid >> 5;
    const int m0 = blockIdx.x * 64;
    const int ar = tid >> 2;
    const int ak = (tid & 3) * 8;
    const int bk = tid >> 3;
    const int bc = (tid & 7) * 16;

    float acc[8][4] = {};

    for (int kt = 0; kt < K; kt += 32) {
        float4 v0 = {0.f,0.f,0.f,0.f}, v1 = {0.f,0.f,0.f,0.f};
        int grow = m0 + ar;
        if (grow < NNODES) {
            const float* s = A + (size_t)grow * K + kt + ak;
            v0 = *(const float4*)(s);
            v1 = *(const float4*)(s + 4);
            if (RELU_IN) {
                v0.x = fmaxf(v0.x, 0.f); v0.y = fmaxf(v0.y, 0.f);
                v0.z = fmaxf(v0.z, 0.f); v0.w = fmaxf(v0.w, 0.f);
                v1.x = fmaxf(v1.x, 0.f); v1.y = fmaxf(v1.y, 0.f);
                v1.z = fmaxf(v1.z, 0.f); v1.w = fmaxf(v1.w, 0.f);
            }
        }
        As[ak + 0][ar] = v0.x; As[ak + 1][ar] = v0.y;
        As[ak + 2][ar] = v0.z; As[ak + 3][ar] = v0.w;
        As[ak + 4][ar] = v1.x; As[ak + 5][ar] = v1.y;
        As[ak + 6][ar] = v1.z; As[ak + 7][ar] = v1.w;
        {
            const float* s = W + (size_t)(kt + bk) * HID + bc;
            float4 w0 = *(const float4*)(s);
            float4 w1 = *(const float4*)(s + 4);
            float4 w2 = *(const float4*)(s + 8);
            float4 w3 = *(const float4*)(s + 12);
            *(float4*)&Bs[bk][bc + 0]  = w0;
            *(float4*)&Bs[bk][bc + 4]  = w1;
            *(float4*)&Bs[bk][bc + 8]  = w2;
            *(float4*)&Bs[bk][bc + 12] = w3;
        }
        __syncthreads();
        #pragma unroll
        for (int k = 0; k < 32; ++k) {
            float a[8], b[4];
            *(float4*)(a)     = *(const float4*)&As[k][ty * 8];
            *(float4*)(a + 4) = *(const float4*)&As[k][ty * 8 + 4];
            *(float4*)(b)     = *(const float4*)&Bs[k][tx * 4];
            #pragma unroll
            for (int i = 0; i < 8; ++i)
                #pragma unroll
                for (int j = 0; j < 4; ++j)
                    acc[i][j] = fmaf(a[i], b[j], acc[i][j]);
        }
        __syncthreads();
    }

    float4 bb = *(const float4*)&bias[tx * 4];
    #pragma unroll
    for (int i = 0; i < 8; ++i) {
        int r = m0 + ty * 8 + i;
        if (r < NNODES) {
            float sn = selfn[r];
            float4 h;
            h.x = acc[i][0]; h.y = acc[i][1]; h.z = acc[i][2]; h.w = acc[i][3];
            *(float4*)&hw[(size_t)r * HID + tx * 4] = h;
            float4 g;
            g.x = fmaf(h.x, sn, bb.x);
            g.y = fmaf(h.y, sn, bb.y);
            g.z = fmaf(h.z, sn, bb.z);
            g.w = fmaf(h.w, sn, bb.w);
            *(float4*)&ag[(size_t)r * HID + tx * 4] = g;
        }
    }
}

// one wave per node; lane handles 2 features
__global__ __launch_bounds__(256) void k_gather(const int* __restrict__ rowptr,
                                                const int* __restrict__ csr,
                                                const float* __restrict__ dis,
                                                const float* __restrict__ hw,
                                                float* __restrict__ ag) {
    int node = blockIdx.x * 4 + (threadIdx.x >> 6);
    if (node >= NNODES) return;
    int lane = threadIdx.x & 63;
    int beg = rowptr[node], end = rowptr[node + 1];
    float dd = dis[node];
    float2* agp = (float2*)&ag[(size_t)node * HID + lane * 2];
    float2 acc = *agp;
    int e = beg;
    for (; e + 1 < end; e += 2) {
        int s0 = csr[e], s1 = csr[e + 1];
        float w0 = dis[s0] * dd, w1 = dis[s1] * dd;
        float2 h0 = *(const float2*)&hw[(size_t)s0 * HID + lane * 2];
        float2 h1 = *(const float2*)&hw[(size_t)s1 * HID + lane * 2];
        acc.x += h0.x * w0 + h1.x * w1;
        acc.y += h0.y * w0 + h1.y * w1;
    }
    if (e < end) {
        int s0 = csr[e];
        float w0 = dis[s0] * dd;
        float2 h0 = *(const float2*)&hw[(size_t)s0 * HID + lane * 2];
        acc.x += h0.x * w0;
        acc.y += h0.y * w0;
    }
    *agp = acc;
}

// one graph per block, 1024 threads: 8 rows in flight per feature
__global__ __launch_bounds__(1024) void k_pool_bn(const float* __restrict__ h,
                                                  const int* __restrict__ batch,
                                                  const float* __restrict__ gamma,
                                                  const float* __restrict__ beta,
                                                  const float* __restrict__ mean,
                                                  const float* __restrict__ var,
                                                  float* __restrict__ xb) {
    int g = blockIdx.x;
    int tid = threadIdx.x;
    int f = tid & 127, r = tid >> 7;   // r in 0..7
    int a = 0, b = NNODES;
    while (a < b) { int m = (a + b) >> 1; if (batch[m] < g) a = m + 1; else b = m; }
    int s1 = a;
    b = NNODES;
    while (a < b) { int m = (a + b) >> 1; if (batch[m] < g + 1) a = m + 1; else b = m; }
    int e1 = a;
    float sum = 0.f;
    for (int i = s1 + r; i < e1; i += 8) sum += fmaxf(0.f, h[(size_t)i * HID + f]);
    __shared__ float red[8][128];
    red[r][f] = sum;
    __syncthreads();
    if (r == 0) {
        float s = red[0][f] + red[1][f] + red[2][f] + red[3][f]
                + red[4][f] + red[5][f] + red[6][f] + red[7][f];
        float cnt = (float)((e1 - s1) > 0 ? (e1 - s1) : 1);
        float pooled = s / cnt;
        float xbv = (pooled - mean[f]) * rsqrtf(var[f] + BN_EPS_C) * gamma[f] + beta[f];
        xb[g * HID + f] = xbv;
    }
}

__global__ __launch_bounds__(256) void k_head(const float* __restrict__ xb,
                                              const float* __restrict__ lw,
                                              const float* __restrict__ lb,
                                              float* __restrict__ out2) {
    int t = threadIdx.x;
    int g = t >> 1, c = t & 1;
    float s = lb[c];
    #pragma unroll
    for (int f = 0; f < HID; ++f) s = fmaf(xb[g * HID + f], lw[f * 2 + c], s);
    out2[t] = fmaxf(s, 0.f);
}

extern "C" void kernel_launch(void* const* d_in, const int* in_sizes, int n_in,
                              void* d_out, int out_size, void* d_ws, size_t ws_size,
                              hipStream_t stream) {
    const float* x     = (const float*)d_in[0];
    const int*   ei    = (const int*)d_in[1];
    const int*   batch = (const int*)d_in[3];
    const float* W1 = (const float*)d_in[4];
    const float* b1 = (const float*)d_in[5];
    const float* W2 = (const float*)d_in[6];
    const float* b2 = (const float*)d_in[7];
    const float* W3 = (const float*)d_in[8];
    const float* b3 = (const float*)d_in[9];
    const float* gamma = (const float*)d_in[10];
    const float* beta  = (const float*)d_in[11];
    const float* mean  = (const float*)d_in[12];
    const float* var   = (const float*)d_in[13];
    const float* lw = (const float*)d_in[14];
    const float* lb = (const float*)d_in[15];
    float* out = (float*)d_out;

    float* HW     = (float*)d_ws;                      // N*128 f
    float* AG     = HW + (size_t)NNODES * HID;         // N*128 f
    float* DIS    = AG + (size_t)NNODES * HID;         // N f
    float* SELFN  = DIS + NNODES;                      // N f
    int*   CNT    = (int*)(SELFN + NNODES);            // N i
    int*   ROWPTR = CNT + NNODES;                      // N+1 i
    int*   BSUM   = ROWPTR + NNODES + 64;              // SB i
    int*   CSR    = BSUM + ((SB + 63) & ~63);          // E i
    // build-phase aliases (dead before first gemm writes HW/AG)
    int*   PAIRS  = (int*)HW;                          // E i   (consumed by kb2 before gemm1)
    int*   HIST   = (int*)AG;                          // NB*NW i (consumed by kbB/kbC before gemm1)
    int*   OFF    = HIST + NB * NW;                    // NB*NW i

    const int* srcv = ei;
    const int* dstv = ei + NEDGES;

    const int gN = (NNODES + 255) / 256;
    const int gE = (NEDGES + 255) / 256;

    // ---- degree / norm / rowptr ----
    k_zero_cnt<<<gN, 256, 0, stream>>>(CNT);
    k_count<<<gE, 256, 0, stream>>>(dstv, CNT);
    k_norm<<<gN, 256, 0, stream>>>(CNT, DIS, SELFN);
    k_scan1<<<SB, 256, 0, stream>>>(CNT, BSUM);
    k_scan2<<<1, 512, 0, stream>>>(BSUM);
    k_scan3<<<SB, 256, 0, stream>>>(CNT, BSUM, ROWPTR);
    // ---- CSR build: histogram -> scan -> scatter -> place ----
    kbA<<<NW, 256, 0, stream>>>(dstv, HIST);
    kbB<<<NB, 256, 0, stream>>>(ROWPTR, HIST, OFF);
    kbC<<<NW, 256, 0, stream>>>(srcv, dstv, OFF, PAIRS);
    kb2<<<NB, 256, 0, stream>>>(ROWPTR, PAIRS, CSR);

    dim3 gg((NNODES + 63) / 64);
    const int ggat = (NNODES + 3) / 4;

    // layer 1
    k_gemm<FIN, false><<<gg, 256, 0, stream>>>(x, W1, b1, SELFN, HW, AG);
    k_gather<<<ggat, 256, 0, stream>>>(ROWPTR, CSR, DIS, HW, AG);
    // layer 2
    k_gemm<HID, true><<<gg, 256, 0, stream>>>(AG, W2, b2, SELFN, HW, AG);
    k_gather<<<ggat, 256, 0, stream>>>(ROWPTR, CSR, DIS, HW, AG);
    // layer 3
    k_gemm<HID, true><<<gg, 256, 0, stream>>>(AG, W3, b3, SELFN, HW, AG);
    k_gather<<<ggat, 256, 0, stream>>>(ROWPTR, CSR, DIS, HW, AG);

    k_pool_bn<<<NG, 1024, 0, stream>>>(AG, batch, gamma, beta, mean, var, out);
    k_head<<<1, 256, 0, stream>>>(out, lw, lb, out + (size_t)NG * HID);
}

// Round 5
// 592.483 us; speedup vs baseline: 4.3023x; 1.3219x over previous
//
#include <hip/hip_runtime.h>

#define NNODES 100000
#define NEDGES 1600000
#define FIN 256
#define HID 128
#define NG 128
#define SB 391            // ceil(NNODES/256)
#define NB 391            // buckets of 256 nodes (dst>>8)
#define NW 256            // histogram workgroups
#define EPW 6250          // NEDGES / NW

static constexpr float BN_EPS_C = 1e-5f;

__device__ __forceinline__ float b2f(unsigned short u) {
    union { unsigned int i; float f; } c; c.i = ((unsigned int)u) << 16; return c.f;
}
__device__ __forceinline__ unsigned short f2b(float f) {
    union { float f; unsigned int i; } c; c.f = f;
    unsigned int u = c.i;
    u += 0x7fffu + ((u >> 16) & 1u);   // round-to-nearest-even
    return (unsigned short)(u >> 16);
}

__global__ __launch_bounds__(256) void k_zero_cnt(int* __restrict__ cnt) {
    int i = blockIdx.x * 256 + threadIdx.x;
    if (i < NNODES) cnt[i] = 0;
}

__global__ __launch_bounds__(256) void k_count(const int* __restrict__ dst, int* __restrict__ cnt) {
    int e = blockIdx.x * 256 + threadIdx.x;
    if (e < NEDGES) atomicAdd(&cnt[dst[e]], 1);
}

// dis = rsqrt(1+cnt); selfn = 1/(1+cnt)
__global__ __launch_bounds__(256) void k_norm(const int* __restrict__ cnt,
                                              float* __restrict__ dis,
                                              float* __restrict__ selfn) {
    int i = blockIdx.x * 256 + threadIdx.x;
    if (i < NNODES) {
        float d = 1.0f + (float)cnt[i];
        dis[i] = rsqrtf(d);
        selfn[i] = 1.0f / d;
    }
}

__global__ __launch_bounds__(256) void k_scan1(const int* __restrict__ cnt, int* __restrict__ bsum) {
    __shared__ int s[256];
    int t = threadIdx.x;
    int i = blockIdx.x * 256 + t;
    s[t] = (i < NNODES) ? cnt[i] : 0;
    __syncthreads();
    for (int off = 128; off > 0; off >>= 1) {
        if (t < off) s[t] += s[t + off];
        __syncthreads();
    }
    if (t == 0) bsum[blockIdx.x] = s[0];
}

__global__ __launch_bounds__(512) void k_scan2(int* __restrict__ bsum) {
    __shared__ int s[512];
    int t = threadIdx.x;
    int v = (t < SB) ? bsum[t] : 0;
    s[t] = v;
    __syncthreads();
    for (int off = 1; off < 512; off <<= 1) {
        int a = (t >= off) ? s[t - off] : 0;
        __syncthreads();
        s[t] += a;
        __syncthreads();
    }
    if (t < SB) bsum[t] = s[t] - v;   // exclusive
}

__global__ __launch_bounds__(256) void k_scan3(const int* __restrict__ cnt,
                                               const int* __restrict__ bsum,
                                               int* __restrict__ rowptr) {
    __shared__ int s[256];
    int t = threadIdx.x;
    int i = blockIdx.x * 256 + t;
    int v = (i < NNODES) ? cnt[i] : 0;
    s[t] = v;
    __syncthreads();
    for (int off = 1; off < 256; off <<= 1) {
        int a = (t >= off) ? s[t - off] : 0;
        __syncthreads();
        s[t] += a;
        __syncthreads();
    }
    int ex = s[t] - v + bsum[blockIdx.x];
    if (i < NNODES) rowptr[i] = ex;
    if (i == 0) rowptr[NNODES] = NEDGES;
}

// pass A: per-WG LDS histogram over 391 buckets
__global__ __launch_bounds__(256) void kbA(const int* __restrict__ dst, int* __restrict__ hist) {
    __shared__ int h[NB];
    int w = blockIdx.x, t = threadIdx.x;
    for (int i = t; i < NB; i += 256) h[i] = 0;
    __syncthreads();
    int base = w * EPW;
    for (int i = t; i < EPW; i += 256) atomicAdd(&h[dst[base + i] >> 8], 1);
    __syncthreads();
    for (int i = t; i < NB; i += 256) hist[i * NW + w] = h[i];
}

// pass B: per-bucket exclusive scan across WGs + bucket base
__global__ __launch_bounds__(256) void kbB(const int* __restrict__ rowptr,
                                           const int* __restrict__ hist,
                                           int* __restrict__ off) {
    __shared__ int s[NW];
    int b = blockIdx.x, t = threadIdx.x;
    int v = hist[b * NW + t];
    s[t] = v;
    __syncthreads();
    for (int o = 1; o < NW; o <<= 1) {
        int a = (t >= o) ? s[t - o] : 0;
        __syncthreads();
        s[t] += a;
        __syncthreads();
    }
    off[b * NW + t] = s[t] - v + rowptr[b * 256];
}

// pass C: scatter packed (src<<8 | dstLow) to exact disjoint positions
__global__ __launch_bounds__(256) void kbC(const int* __restrict__ src,
                                           const int* __restrict__ dst,
                                           const int* __restrict__ off,
                                           int* __restrict__ pairs) {
    __shared__ int cur[NB];
    int w = blockIdx.x, t = threadIdx.x;
    for (int i = t; i < NB; i += 256) cur[i] = off[i * NW + w];
    __syncthreads();
    int base = w * EPW;
    for (int i = t; i < EPW; i += 256) {
        int d = dst[base + i];
        int pos = atomicAdd(&cur[d >> 8], 1);
        pairs[pos] = (src[base + i] << 8) | (d & 255);
    }
}

// within-bucket placement via LDS per-node cursors (256 nodes/bucket)
__global__ __launch_bounds__(256) void kb2(const int* __restrict__ rowptr,
                                           const int* __restrict__ pairs,
                                           int* __restrict__ csr) {
    int b = blockIdx.x;
    int nbase = b * 256;
    int nmax = NNODES - nbase; if (nmax > 256) nmax = 256;
    __shared__ int cur[256];
    int t = threadIdx.x;
    if (t < nmax) cur[t] = rowptr[nbase + t];
    __syncthreads();
    int beg = rowptr[nbase];
    int end = rowptr[nbase + nmax];
    for (int i = beg + t; i < end; i += 256) {
        int p = pairs[i];
        int pos = atomicAdd(&cur[p & 255], 1);
        csr[pos] = p >> 8;
    }
}

// GEMM: hw = A[N,K] @ W[K,128]; hwb = bf16(hw); ag = hw*selfn[row] + bias[col] (fp32)
template<int K, bool RELU_IN>
__global__ __launch_bounds__(256) void k_gemm(const float* __restrict__ A,
                                              const float* __restrict__ W,
                                              const float* __restrict__ bias,
                                              const float* __restrict__ selfn,
                                              unsigned short* __restrict__ hwb,
                                              float* __restrict__ ag) {
    __shared__ float As[32][68];
    __shared__ float Bs[32][132];
    const int tid = threadIdx.x;
    const int tx = tid & 31;
    const int ty = tid >> 5;
    const int m0 = blockIdx.x * 64;
    const int ar = tid >> 2;
    const int ak = (tid & 3) * 8;
    const int bk = tid >> 3;
    const int bc = (tid & 7) * 16;

    float acc[8][4] = {};

    for (int kt = 0; kt < K; kt += 32) {
        float4 v0 = {0.f,0.f,0.f,0.f}, v1 = {0.f,0.f,0.f,0.f};
        int grow = m0 + ar;
        if (grow < NNODES) {
            const float* s = A + (size_t)grow * K + kt + ak;
            v0 = *(const float4*)(s);
            v1 = *(const float4*)(s + 4);
            if (RELU_IN) {
                v0.x = fmaxf(v0.x, 0.f); v0.y = fmaxf(v0.y, 0.f);
                v0.z = fmaxf(v0.z, 0.f); v0.w = fmaxf(v0.w, 0.f);
                v1.x = fmaxf(v1.x, 0.f); v1.y = fmaxf(v1.y, 0.f);
                v1.z = fmaxf(v1.z, 0.f); v1.w = fmaxf(v1.w, 0.f);
            }
        }
        As[ak + 0][ar] = v0.x; As[ak + 1][ar] = v0.y;
        As[ak + 2][ar] = v0.z; As[ak + 3][ar] = v0.w;
        As[ak + 4][ar] = v1.x; As[ak + 5][ar] = v1.y;
        As[ak + 6][ar] = v1.z; As[ak + 7][ar] = v1.w;
        {
            const float* s = W + (size_t)(kt + bk) * HID + bc;
            float4 w0 = *(const float4*)(s);
            float4 w1 = *(const float4*)(s + 4);
            float4 w2 = *(const float4*)(s + 8);
            float4 w3 = *(const float4*)(s + 12);
            *(float4*)&Bs[bk][bc + 0]  = w0;
            *(float4*)&Bs[bk][bc + 4]  = w1;
            *(float4*)&Bs[bk][bc + 8]  = w2;
            *(float4*)&Bs[bk][bc + 12] = w3;
        }
        __syncthreads();
        #pragma unroll
        for (int k = 0; k < 32; ++k) {
            float a[8], b[4];
            *(float4*)(a)     = *(const float4*)&As[k][ty * 8];
            *(float4*)(a + 4) = *(const float4*)&As[k][ty * 8 + 4];
            *(float4*)(b)     = *(const float4*)&Bs[k][tx * 4];
            #pragma unroll
            for (int i = 0; i < 8; ++i)
                #pragma unroll
                for (int j = 0; j < 4; ++j)
                    acc[i][j] = fmaf(a[i], b[j], acc[i][j]);
        }
        __syncthreads();
    }

    float4 bb = *(const float4*)&bias[tx * 4];
    #pragma unroll
    for (int i = 0; i < 8; ++i) {
        int r = m0 + ty * 8 + i;
        if (r < NNODES) {
            float sn = selfn[r];
            ushort4 hb;
            hb.x = f2b(acc[i][0]); hb.y = f2b(acc[i][1]);
            hb.z = f2b(acc[i][2]); hb.w = f2b(acc[i][3]);
            *(ushort4*)&hwb[(size_t)r * HID + tx * 4] = hb;
            float4 g;
            g.x = fmaf(acc[i][0], sn, bb.x);
            g.y = fmaf(acc[i][1], sn, bb.y);
            g.z = fmaf(acc[i][2], sn, bb.z);
            g.w = fmaf(acc[i][3], sn, bb.w);
            *(float4*)&ag[(size_t)r * HID + tx * 4] = g;
        }
    }
}

// one wave per node; lane handles 2 features (bf16 rows, fp32 accumulate), 4 edges in flight
__global__ __launch_bounds__(256) void k_gather(const int* __restrict__ rowptr,
                                                const int* __restrict__ csr,
                                                const float* __restrict__ dis,
                                                const unsigned short* __restrict__ hwb,
                                                float* __restrict__ ag) {
    int node = blockIdx.x * 4 + (threadIdx.x >> 6);
    if (node >= NNODES) return;
    int lane = threadIdx.x & 63;
    int beg = rowptr[node], end = rowptr[node + 1];
    float dd = dis[node];
    float2* agp = (float2*)&ag[(size_t)node * HID + lane * 2];
    float2 acc = *agp;
    int e = beg;
    for (; e + 3 < end; e += 4) {
        int s0 = csr[e], s1 = csr[e + 1], s2 = csr[e + 2], s3 = csr[e + 3];
        float w0 = dis[s0] * dd, w1 = dis[s1] * dd;
        float w2 = dis[s2] * dd, w3 = dis[s3] * dd;
        ushort2 a0 = ((const ushort2*)(hwb + (size_t)s0 * HID))[lane];
        ushort2 a1 = ((const ushort2*)(hwb + (size_t)s1 * HID))[lane];
        ushort2 a2 = ((const ushort2*)(hwb + (size_t)s2 * HID))[lane];
        ushort2 a3 = ((const ushort2*)(hwb + (size_t)s3 * HID))[lane];
        acc.x += b2f(a0.x) * w0 + b2f(a1.x) * w1 + b2f(a2.x) * w2 + b2f(a3.x) * w3;
        acc.y += b2f(a0.y) * w0 + b2f(a1.y) * w1 + b2f(a2.y) * w2 + b2f(a3.y) * w3;
    }
    for (; e < end; ++e) {
        int s0 = csr[e];
        float w0 = dis[s0] * dd;
        ushort2 a0 = ((const ushort2*)(hwb + (size_t)s0 * HID))[lane];
        acc.x += b2f(a0.x) * w0;
        acc.y += b2f(a0.y) * w0;
    }
    *agp = acc;
}

// one graph per block, 1024 threads: 8 rows in flight per feature
__global__ __launch_bounds__(1024) void k_pool_bn(const float* __restrict__ h,
                                                  const int* __restrict__ batch,
                                                  const float* __restrict__ gamma,
                                                  const float* __restrict__ beta,
                                                  const float* __restrict__ mean,
                                                  const float* __restrict__ var,
                                                  float* __restrict__ xb) {
    int g = blockIdx.x;
    int tid = threadIdx.x;
    int f = tid & 127, r = tid >> 7;   // r in 0..7
    int a = 0, b = NNODES;
    while (a < b) { int m = (a + b) >> 1; if (batch[m] < g) a = m + 1; else b = m; }
    int s1 = a;
    b = NNODES;
    while (a < b) { int m = (a + b) >> 1; if (batch[m] < g + 1) a = m + 1; else b = m; }
    int e1 = a;
    float sum = 0.f;
    for (int i = s1 + r; i < e1; i += 8) sum += fmaxf(0.f, h[(size_t)i * HID + f]);
    __shared__ float red[8][128];
    red[r][f] = sum;
    __syncthreads();
    if (r == 0) {
        float s = red[0][f] + red[1][f] + red[2][f] + red[3][f]
                + red[4][f] + red[5][f] + red[6][f] + red[7][f];
        float cnt = (float)((e1 - s1) > 0 ? (e1 - s1) : 1);
        float pooled = s / cnt;
        float xbv = (pooled - mean[f]) * rsqrtf(var[f] + BN_EPS_C) * gamma[f] + beta[f];
        xb[g * HID + f] = xbv;
    }
}

__global__ __launch_bounds__(256) void k_head(const float* __restrict__ xb,
                                              const float* __restrict__ lw,
                                              const float* __restrict__ lb,
                                              float* __restrict__ out2) {
    int t = threadIdx.x;
    int g = t >> 1, c = t & 1;
    float s = lb[c];
    #pragma unroll
    for (int f = 0; f < HID; ++f) s = fmaf(xb[g * HID + f], lw[f * 2 + c], s);
    out2[t] = fmaxf(s, 0.f);
}

extern "C" void kernel_launch(void* const* d_in, const int* in_sizes, int n_in,
                              void* d_out, int out_size, void* d_ws, size_t ws_size,
                              hipStream_t stream) {
    const float* x     = (const float*)d_in[0];
    const int*   ei    = (const int*)d_in[1];
    const int*   batch = (const int*)d_in[3];
    const float* W1 = (const float*)d_in[4];
    const float* b1 = (const float*)d_in[5];
    const float* W2 = (const float*)d_in[6];
    const float* b2 = (const float*)d_in[7];
    const float* W3 = (const float*)d_in[8];
    const float* b3 = (const float*)d_in[9];
    const float* gamma = (const float*)d_in[10];
    const float* beta  = (const float*)d_in[11];
    const float* mean  = (const float*)d_in[12];
    const float* var   = (const float*)d_in[13];
    const float* lw = (const float*)d_in[14];
    const float* lb = (const float*)d_in[15];
    float* out = (float*)d_out;

    unsigned short* HWB = (unsigned short*)d_ws;               // N*128 u16 (25.6MB)
    float* AG     = (float*)((char*)d_ws + (size_t)NNODES * HID * 2); // N*128 f
    float* DIS    = AG + (size_t)NNODES * HID;         // N f
    float* SELFN  = DIS + NNODES;                      // N f
    int*   CNT    = (int*)(SELFN + NNODES);            // N i
    int*   ROWPTR = CNT + NNODES;                      // N+1 i
    int*   BSUM   = ROWPTR + NNODES + 64;              // SB i
    int*   CSR    = BSUM + ((SB + 63) & ~63);          // E i
    // build-phase aliases (dead before first gemm writes HWB/AG)
    int*   PAIRS  = (int*)HWB;                         // E i (6.4MB <= 25.6MB)
    int*   HIST   = (int*)AG;                          // NB*NW i
    int*   OFF    = HIST + NB * NW;                    // NB*NW i

    const int* srcv = ei;
    const int* dstv = ei + NEDGES;

    const int gN = (NNODES + 255) / 256;
    const int gE = (NEDGES + 255) / 256;

    // ---- degree / norm / rowptr ----
    k_zero_cnt<<<gN, 256, 0, stream>>>(CNT);
    k_count<<<gE, 256, 0, stream>>>(dstv, CNT);
    k_norm<<<gN, 256, 0, stream>>>(CNT, DIS, SELFN);
    k_scan1<<<SB, 256, 0, stream>>>(CNT, BSUM);
    k_scan2<<<1, 512, 0, stream>>>(BSUM);
    k_scan3<<<SB, 256, 0, stream>>>(CNT, BSUM, ROWPTR);
    // ---- CSR build: histogram -> scan -> scatter -> place ----
    kbA<<<NW, 256, 0, stream>>>(dstv, HIST);
    kbB<<<NB, 256, 0, stream>>>(ROWPTR, HIST, OFF);
    kbC<<<NW, 256, 0, stream>>>(srcv, dstv, OFF, PAIRS);
    kb2<<<NB, 256, 0, stream>>>(ROWPTR, PAIRS, CSR);

    dim3 gg((NNODES + 63) / 64);
    const int ggat = (NNODES + 3) / 4;

    // layer 1
    k_gemm<FIN, false><<<gg, 256, 0, stream>>>(x, W1, b1, SELFN, HWB, AG);
    k_gather<<<ggat, 256, 0, stream>>>(ROWPTR, CSR, DIS, HWB, AG);
    // layer 2
    k_gemm<HID, true><<<gg, 256, 0, stream>>>(AG, W2, b2, SELFN, HWB, AG);
    k_gather<<<ggat, 256, 0, stream>>>(ROWPTR, CSR, DIS, HWB, AG);
    // layer 3
    k_gemm<HID, true><<<gg, 256, 0, stream>>>(AG, W3, b3, SELFN, HWB, AG);
    k_gather<<<ggat, 256, 0, stream>>>(ROWPTR, CSR, DIS, HWB, AG);

    k_pool_bn<<<NG, 1024, 0, stream>>>(AG, batch, gamma, beta, mean, var, out);
    k_head<<<1, 256, 0, stream>>>(out, lw, lb, out + (size_t)NG * HID);
}

// Round 6
// 498.550 us; speedup vs baseline: 5.1129x; 1.1884x over previous
//
#include <hip/hip_runtime.h>

#define NNODES 100000
#define NEDGES 1600000
#define FIN 256
#define HID 128
#define NG 128
#define SB 391            // ceil(NNODES/256)
#define NB 391            // buckets of 256 nodes (dst>>8)
#define NW 256            // histogram workgroups
#define EPW 6250          // NEDGES / NW

static constexpr float BN_EPS_C = 1e-5f;

typedef __attribute__((ext_vector_type(8))) short bf16x8;
typedef __attribute__((ext_vector_type(4))) float f32x4;

__device__ __forceinline__ float b2f(unsigned short u) {
    union { unsigned int i; float f; } c; c.i = ((unsigned int)u) << 16; return c.f;
}
__device__ __forceinline__ unsigned short f2b(float f) {
    union { float f; unsigned int i; } c; c.f = f;
    unsigned int u = c.i;
    u += 0x7fffu + ((u >> 16) & 1u);   // round-to-nearest-even
    return (unsigned short)(u >> 16);
}

__global__ __launch_bounds__(256) void k_zero_cnt(int* __restrict__ cnt) {
    int i = blockIdx.x * 256 + threadIdx.x;
    if (i < NNODES) cnt[i] = 0;
}

__global__ __launch_bounds__(256) void k_count(const int* __restrict__ dst, int* __restrict__ cnt) {
    int e = blockIdx.x * 256 + threadIdx.x;
    if (e < NEDGES) atomicAdd(&cnt[dst[e]], 1);
}

__global__ __launch_bounds__(256) void k_norm(const int* __restrict__ cnt,
                                              float* __restrict__ dis,
                                              float* __restrict__ selfn) {
    int i = blockIdx.x * 256 + threadIdx.x;
    if (i < NNODES) {
        float d = 1.0f + (float)cnt[i];
        dis[i] = rsqrtf(d);
        selfn[i] = 1.0f / d;
    }
}

__global__ __launch_bounds__(256) void k_scan1(const int* __restrict__ cnt, int* __restrict__ bsum) {
    __shared__ int s[256];
    int t = threadIdx.x;
    int i = blockIdx.x * 256 + t;
    s[t] = (i < NNODES) ? cnt[i] : 0;
    __syncthreads();
    for (int off = 128; off > 0; off >>= 1) {
        if (t < off) s[t] += s[t + off];
        __syncthreads();
    }
    if (t == 0) bsum[blockIdx.x] = s[0];
}

__global__ __launch_bounds__(512) void k_scan2(int* __restrict__ bsum) {
    __shared__ int s[512];
    int t = threadIdx.x;
    int v = (t < SB) ? bsum[t] : 0;
    s[t] = v;
    __syncthreads();
    for (int off = 1; off < 512; off <<= 1) {
        int a = (t >= off) ? s[t - off] : 0;
        __syncthreads();
        s[t] += a;
        __syncthreads();
    }
    if (t < SB) bsum[t] = s[t] - v;   // exclusive
}

__global__ __launch_bounds__(256) void k_scan3(const int* __restrict__ cnt,
                                               const int* __restrict__ bsum,
                                               int* __restrict__ rowptr) {
    __shared__ int s[256];
    int t = threadIdx.x;
    int i = blockIdx.x * 256 + t;
    int v = (i < NNODES) ? cnt[i] : 0;
    s[t] = v;
    __syncthreads();
    for (int off = 1; off < 256; off <<= 1) {
        int a = (t >= off) ? s[t - off] : 0;
        __syncthreads();
        s[t] += a;
        __syncthreads();
    }
    int ex = s[t] - v + bsum[blockIdx.x];
    if (i < NNODES) rowptr[i] = ex;
    if (i == 0) rowptr[NNODES] = NEDGES;
}

__global__ __launch_bounds__(256) void kbA(const int* __restrict__ dst, int* __restrict__ hist) {
    __shared__ int h[NB];
    int w = blockIdx.x, t = threadIdx.x;
    for (int i = t; i < NB; i += 256) h[i] = 0;
    __syncthreads();
    int base = w * EPW;
    for (int i = t; i < EPW; i += 256) atomicAdd(&h[dst[base + i] >> 8], 1);
    __syncthreads();
    for (int i = t; i < NB; i += 256) hist[i * NW + w] = h[i];
}

__global__ __launch_bounds__(256) void kbB(const int* __restrict__ rowptr,
                                           const int* __restrict__ hist,
                                           int* __restrict__ off) {
    __shared__ int s[NW];
    int b = blockIdx.x, t = threadIdx.x;
    int v = hist[b * NW + t];
    s[t] = v;
    __syncthreads();
    for (int o = 1; o < NW; o <<= 1) {
        int a = (t >= o) ? s[t - o] : 0;
        __syncthreads();
        s[t] += a;
        __syncthreads();
    }
    off[b * NW + t] = s[t] - v + rowptr[b * 256];
}

__global__ __launch_bounds__(256) void kbC(const int* __restrict__ src,
                                           const int* __restrict__ dst,
                                           const int* __restrict__ off,
                                           int* __restrict__ pairs) {
    __shared__ int cur[NB];
    int w = blockIdx.x, t = threadIdx.x;
    for (int i = t; i < NB; i += 256) cur[i] = off[i * NW + w];
    __syncthreads();
    int base = w * EPW;
    for (int i = t; i < EPW; i += 256) {
        int d = dst[base + i];
        int pos = atomicAdd(&cur[d >> 8], 1);
        pairs[pos] = (src[base + i] << 8) | (d & 255);
    }
}

__global__ __launch_bounds__(256) void kb2(const int* __restrict__ rowptr,
                                           const int* __restrict__ pairs,
                                           int* __restrict__ csr) {
    int b = blockIdx.x;
    int nbase = b * 256;
    int nmax = NNODES - nbase; if (nmax > 256) nmax = 256;
    __shared__ int cur[256];
    int t = threadIdx.x;
    if (t < nmax) cur[t] = rowptr[nbase + t];
    __syncthreads();
    int beg = rowptr[nbase];
    int end = rowptr[nbase + nmax];
    for (int i = beg + t; i < end; i += 256) {
        int p = pairs[i];
        int pos = atomicAdd(&cur[p & 255], 1);
        csr[pos] = p >> 8;
    }
}

// Convert W[K,128] fp32 -> hi/lo bf16 in MFMA frag-major layout:
// whl[kstep][plane][tile][lane][j]; lane=(c&15)+16*((k&31)>>3), j=k&7, tile=c>>4
__global__ __launch_bounds__(256) void k_wconv(const float* __restrict__ W,
                                               unsigned short* __restrict__ whl,
                                               int K) {
    int idx = blockIdx.x * 256 + threadIdx.x;
    if (idx >= K * 128) return;
    int k = idx >> 7, c = idx & 127;
    float v = W[k * 128 + c];
    unsigned short hi = f2b(v);
    unsigned short lo = f2b(v - b2f(hi));
    int kstep = k >> 5, kk = k & 31, g = kk >> 3, j = kk & 7;
    int tile = c >> 4, lane = (c & 15) + 16 * g;
    size_t b0 = ((((size_t)kstep * 2 + 0) * 8 + tile) * 64 + lane) * 8 + j;
    size_t b1 = ((((size_t)kstep * 2 + 1) * 8 + tile) * 64 + lane) * 8 + j;
    whl[b0] = hi;
    whl[b1] = lo;
}

// MFMA split-bf16 GEMM: hw = A[N,K] @ W[K,128]; hwb = bf16(hw); ag = hw*selfn + bias
// 64 rows/block, 4 waves, wave w owns rows w*16..w*16+15, all 128 cols (8 col-tiles).
template<int K, bool RELU_IN>
__global__ __launch_bounds__(256) void k_gemm_mfma(const float* __restrict__ A,
                                                   const unsigned short* __restrict__ whl,
                                                   const float* __restrict__ bias,
                                                   const float* __restrict__ selfn,
                                                   unsigned short* __restrict__ hwb,
                                                   float* __restrict__ ag) {
    __shared__ __align__(16) unsigned short Ah0[2048];  // [tile4][lane64][8] hi
    __shared__ __align__(16) unsigned short Ah1[2048];  // lo
    __shared__ __align__(16) unsigned short Bs[8192];   // [plane2][tile8][lane64][8]

    const int tid = threadIdx.x;
    const int w = tid >> 6;
    const int lane = tid & 63;
    const int m0 = blockIdx.x * 64;
    // A staging: thread -> (row ar, k-offset ak), frag-major dest
    const int ar = tid >> 2;
    const int ak = (tid & 3) * 8;
    const int adst = (((ar >> 4) * 64) + (ar & 15) + 16 * (ak >> 3)) * 8;

    f32x4 acc[8] = {};

    for (int kt = 0; kt < K; kt += 32) {
        // ---- stage A (fp32 -> hi/lo bf16, frag-major) ----
        {
            float4 v0 = {0.f,0.f,0.f,0.f}, v1 = {0.f,0.f,0.f,0.f};
            int grow = m0 + ar;
            if (grow < NNODES) {
                const float* s = A + (size_t)grow * K + kt + ak;
                v0 = *(const float4*)(s);
                v1 = *(const float4*)(s + 4);
                if (RELU_IN) {
                    v0.x = fmaxf(v0.x, 0.f); v0.y = fmaxf(v0.y, 0.f);
                    v0.z = fmaxf(v0.z, 0.f); v0.w = fmaxf(v0.w, 0.f);
                    v1.x = fmaxf(v1.x, 0.f); v1.y = fmaxf(v1.y, 0.f);
                    v1.z = fmaxf(v1.z, 0.f); v1.w = fmaxf(v1.w, 0.f);
                }
            }
            float av[8];
            *(float4*)(av) = v0; *(float4*)(av + 4) = v1;
            bf16x8 hv, lv;
            #pragma unroll
            for (int j = 0; j < 8; ++j) {
                unsigned short h = f2b(av[j]);
                hv[j] = (short)h;
                lv[j] = (short)f2b(av[j] - b2f(h));
            }
            *(bf16x8*)&Ah0[adst] = hv;
            *(bf16x8*)&Ah1[adst] = lv;
        }
        // ---- stage B (linear copy of preconverted frag-major hi/lo) ----
        {
            const float4* bsrc = (const float4*)(whl + (size_t)(kt >> 5) * 8192);
            float4* bdst = (float4*)Bs;
            #pragma unroll
            for (int i = 0; i < 4; ++i) bdst[tid * 4 + i] = bsrc[tid * 4 + i];
        }
        __syncthreads();
        // ---- MFMA: (ah+al)(bh+bl) ~= ah*bh + ah*bl + al*bh ----
        bf16x8 a0 = *(const bf16x8*)&Ah0[(w * 64 + lane) * 8];
        bf16x8 a1 = *(const bf16x8*)&Ah1[(w * 64 + lane) * 8];
        #pragma unroll
        for (int t = 0; t < 8; ++t) {
            bf16x8 b0 = *(const bf16x8*)&Bs[(t * 64 + lane) * 8];
            bf16x8 b1 = *(const bf16x8*)&Bs[4096 + (t * 64 + lane) * 8];
            acc[t] = __builtin_amdgcn_mfma_f32_16x16x32_bf16(a0, b0, acc[t], 0, 0, 0);
            acc[t] = __builtin_amdgcn_mfma_f32_16x16x32_bf16(a0, b1, acc[t], 0, 0, 0);
            acc[t] = __builtin_amdgcn_mfma_f32_16x16x32_bf16(a1, b0, acc[t], 0, 0, 0);
        }
        __syncthreads();
    }

    // ---- epilogue: C/D layout col=lane&15, row=(lane>>4)*4+i ----
    const int colLo = lane & 15;
    const int gq = lane >> 4;
    float bbv[8];
    #pragma unroll
    for (int t = 0; t < 8; ++t) bbv[t] = bias[t * 16 + colLo];
    #pragma unroll
    for (int i = 0; i < 4; ++i) {
        int row = m0 + w * 16 + gq * 4 + i;
        if (row < NNODES) {
            float sn = selfn[row];
            #pragma unroll
            for (int t = 0; t < 8; ++t) {
                int col = t * 16 + colLo;
                float v = acc[t][i];
                hwb[(size_t)row * HID + col] = f2b(v);
                ag[(size_t)row * HID + col] = fmaf(v, sn, bbv[t]);
            }
        }
    }
}

// one wave per node; lane handles 2 features (bf16 rows, fp32 accumulate), 4 edges in flight
__global__ __launch_bounds__(256) void k_gather(const int* __restrict__ rowptr,
                                                const int* __restrict__ csr,
                                                const float* __restrict__ dis,
                                                const unsigned short* __restrict__ hwb,
                                                float* __restrict__ ag) {
    int node = blockIdx.x * 4 + (threadIdx.x >> 6);
    if (node >= NNODES) return;
    int lane = threadIdx.x & 63;
    int beg = rowptr[node], end = rowptr[node + 1];
    float dd = dis[node];
    float2* agp = (float2*)&ag[(size_t)node * HID + lane * 2];
    float2 acc = *agp;
    int e = beg;
    for (; e + 3 < end; e += 4) {
        int s0 = csr[e], s1 = csr[e + 1], s2 = csr[e + 2], s3 = csr[e + 3];
        float w0 = dis[s0] * dd, w1 = dis[s1] * dd;
        float w2 = dis[s2] * dd, w3 = dis[s3] * dd;
        ushort2 a0 = ((const ushort2*)(hwb + (size_t)s0 * HID))[lane];
        ushort2 a1 = ((const ushort2*)(hwb + (size_t)s1 * HID))[lane];
        ushort2 a2 = ((const ushort2*)(hwb + (size_t)s2 * HID))[lane];
        ushort2 a3 = ((const ushort2*)(hwb + (size_t)s3 * HID))[lane];
        acc.x += b2f(a0.x) * w0 + b2f(a1.x) * w1 + b2f(a2.x) * w2 + b2f(a3.x) * w3;
        acc.y += b2f(a0.y) * w0 + b2f(a1.y) * w1 + b2f(a2.y) * w2 + b2f(a3.y) * w3;
    }
    for (; e < end; ++e) {
        int s0 = csr[e];
        float w0 = dis[s0] * dd;
        ushort2 a0 = ((const ushort2*)(hwb + (size_t)s0 * HID))[lane];
        acc.x += b2f(a0.x) * w0;
        acc.y += b2f(a0.y) * w0;
    }
    *agp = acc;
}

__global__ __launch_bounds__(1024) void k_pool_bn(const float* __restrict__ h,
                                                  const int* __restrict__ batch,
                                                  const float* __restrict__ gamma,
                                                  const float* __restrict__ beta,
                                                  const float* __restrict__ mean,
                                                  const float* __restrict__ var,
                                                  float* __restrict__ xb) {
    int g = blockIdx.x;
    int tid = threadIdx.x;
    int f = tid & 127, r = tid >> 7;
    int a = 0, b = NNODES;
    while (a < b) { int m = (a + b) >> 1; if (batch[m] < g) a = m + 1; else b = m; }
    int s1 = a;
    b = NNODES;
    while (a < b) { int m = (a + b) >> 1; if (batch[m] < g + 1) a = m + 1; else b = m; }
    int e1 = a;
    float sum = 0.f;
    for (int i = s1 + r; i < e1; i += 8) sum += fmaxf(0.f, h[(size_t)i * HID + f]);
    __shared__ float red[8][128];
    red[r][f] = sum;
    __syncthreads();
    if (r == 0) {
        float s = red[0][f] + red[1][f] + red[2][f] + red[3][f]
                + red[4][f] + red[5][f] + red[6][f] + red[7][f];
        float cnt = (float)((e1 - s1) > 0 ? (e1 - s1) : 1);
        float pooled = s / cnt;
        float xbv = (pooled - mean[f]) * rsqrtf(var[f] + BN_EPS_C) * gamma[f] + beta[f];
        xb[g * HID + f] = xbv;
    }
}

__global__ __launch_bounds__(256) void k_head(const float* __restrict__ xb,
                                              const float* __restrict__ lw,
                                              const float* __restrict__ lb,
                                              float* __restrict__ out2) {
    int t = threadIdx.x;
    int g = t >> 1, c = t & 1;
    float s = lb[c];
    #pragma unroll
    for (int f = 0; f < HID; ++f) s = fmaf(xb[g * HID + f], lw[f * 2 + c], s);
    out2[t] = fmaxf(s, 0.f);
}

extern "C" void kernel_launch(void* const* d_in, const int* in_sizes, int n_in,
                              void* d_out, int out_size, void* d_ws, size_t ws_size,
                              hipStream_t stream) {
    const float* x     = (const float*)d_in[0];
    const int*   ei    = (const int*)d_in[1];
    const int*   batch = (const int*)d_in[3];
    const float* W1 = (const float*)d_in[4];
    const float* b1 = (const float*)d_in[5];
    const float* W2 = (const float*)d_in[6];
    const float* b2 = (const float*)d_in[7];
    const float* W3 = (const float*)d_in[8];
    const float* b3 = (const float*)d_in[9];
    const float* gamma = (const float*)d_in[10];
    const float* beta  = (const float*)d_in[11];
    const float* mean  = (const float*)d_in[12];
    const float* var   = (const float*)d_in[13];
    const float* lw = (const float*)d_in[14];
    const float* lb = (const float*)d_in[15];
    float* out = (float*)d_out;

    unsigned short* HWB = (unsigned short*)d_ws;                      // N*128 u16
    float* AG     = (float*)((char*)d_ws + (size_t)NNODES * HID * 2); // N*128 f
    float* DIS    = AG + (size_t)NNODES * HID;
    float* SELFN  = DIS + NNODES;
    int*   CNT    = (int*)(SELFN + NNODES);
    int*   ROWPTR = CNT + NNODES;
    int*   BSUM   = ROWPTR + NNODES + 64;
    int*   CSR    = BSUM + ((SB + 63) & ~63);
    unsigned short* WHL1 = (unsigned short*)(((uintptr_t)(CSR + NEDGES) + 15) & ~(uintptr_t)15);
    unsigned short* WHL2 = WHL1 + (size_t)FIN * 128 * 2;   // 65536
    unsigned short* WHL3 = WHL2 + (size_t)HID * 128 * 2;   // 32768
    // build-phase aliases (dead before first gemm writes HWB/AG)
    int*   PAIRS  = (int*)HWB;
    int*   HIST   = (int*)AG;
    int*   OFF    = HIST + NB * NW;

    const int* srcv = ei;
    const int* dstv = ei + NEDGES;

    const int gN = (NNODES + 255) / 256;
    const int gE = (NEDGES + 255) / 256;

    // ---- degree / norm / rowptr ----
    k_zero_cnt<<<gN, 256, 0, stream>>>(CNT);
    k_count<<<gE, 256, 0, stream>>>(dstv, CNT);
    k_norm<<<gN, 256, 0, stream>>>(CNT, DIS, SELFN);
    k_scan1<<<SB, 256, 0, stream>>>(CNT, BSUM);
    k_scan2<<<1, 512, 0, stream>>>(BSUM);
    k_scan3<<<SB, 256, 0, stream>>>(CNT, BSUM, ROWPTR);
    // ---- CSR build ----
    kbA<<<NW, 256, 0, stream>>>(dstv, HIST);
    kbB<<<NB, 256, 0, stream>>>(ROWPTR, HIST, OFF);
    kbC<<<NW, 256, 0, stream>>>(srcv, dstv, OFF, PAIRS);
    kb2<<<NB, 256, 0, stream>>>(ROWPTR, PAIRS, CSR);
    // ---- W pre-conversion (hi/lo bf16, frag-major) ----
    k_wconv<<<(FIN * 128 + 255) / 256, 256, 0, stream>>>(W1, WHL1, FIN);
    k_wconv<<<(HID * 128 + 255) / 256, 256, 0, stream>>>(W2, WHL2, HID);
    k_wconv<<<(HID * 128 + 255) / 256, 256, 0, stream>>>(W3, WHL3, HID);

    dim3 gg((NNODES + 63) / 64);
    const int ggat = (NNODES + 3) / 4;

    // layer 1
    k_gemm_mfma<FIN, false><<<gg, 256, 0, stream>>>(x, WHL1, b1, SELFN, HWB, AG);
    k_gather<<<ggat, 256, 0, stream>>>(ROWPTR, CSR, DIS, HWB, AG);
    // layer 2 (in-place AG read/write: block touches only its own rows)
    k_gemm_mfma<HID, true><<<gg, 256, 0, stream>>>(AG, WHL2, b2, SELFN, HWB, AG);
    k_gather<<<ggat, 256, 0, stream>>>(ROWPTR, CSR, DIS, HWB, AG);
    // layer 3
    k_gemm_mfma<HID, true><<<gg, 256, 0, stream>>>(AG, WHL3, b3, SELFN, HWB, AG);
    k_gather<<<ggat, 256, 0, stream>>>(ROWPTR, CSR, DIS, HWB, AG);

    k_pool_bn<<<NG, 1024, 0, stream>>>(AG, batch, gamma, beta, mean, var, out);
    k_head<<<1, 256, 0, stream>>>(out, lw, lb, out + (size_t)NG * HID);
}